// Round 5
// baseline (207.893 us; speedup 1.0000x reference)
//
#include <hip/hip_runtime.h>
#include <stdint.h>

typedef unsigned short u16t;
typedef short s8v __attribute__((ext_vector_type(8)));   // 8 x bf16 (guide §3 frag_ab)
typedef float f4v __attribute__((ext_vector_type(4)));

#define MFMA16 __builtin_amdgcn_mfma_f32_16x16x32_bf16

#define QKN (16*4*512*64)   // elements per Q/K buffer: B*H*L*hd

__device__ __forceinline__ u16t f2bf(float f) {
  unsigned u = __builtin_bit_cast(unsigned, f);
  u += 0x7fffu + ((u >> 16) & 1u);          // RNE
  return (u16t)(u >> 16);
}

// ---------------------------------------------------------------------------
// Canonicalize src_mask into int32[8192].
__global__ __launch_bounds__(256) void mask_norm(const int* __restrict__ raw,
                                                 int* __restrict__ dst) {
  __shared__ int mode;   // 0=int32, 1=bytes, 2=float32
  const int t = threadIdx.x;
  if (t == 0) mode = 0;
  __syncthreads();
  unsigned v0 = (unsigned)raw[t], v1 = (unsigned)raw[t + 256];
  if (v0 == 0x3F800000u || v1 == 0x3F800000u) mode = 2;   // benign race
  __syncthreads();
  if (mode == 0 && (v0 > 1u || v1 > 1u)) mode = 1;
  __syncthreads();
  const int i = blockIdx.x * 256 + t;
  int m;
  if (mode == 2)      m = (((const float*)raw)[i] != 0.0f) ? 1 : 0;
  else if (mode == 1) m = ((const unsigned char*)raw)[i];
  else                m = raw[i];
  dst[i] = m;
}

// ---------------------------------------------------------------------------
// WeffT[p][n][d] = sum_t W2_p[t][n] * Wqk_p[d][aoff+t]   (f32 in, bf16 out).
__global__ __launch_bounds__(256) void weff_kernel(
    const float* __restrict__ Wiqk, const float* __restrict__ Wqi, const float* __restrict__ Wki,
    const float* __restrict__ Wdqk, const float* __restrict__ Wqd, const float* __restrict__ Wkd,
    u16t* __restrict__ weffT) {
  __shared__ float At[16][65];   // At[kk][nn]
  __shared__ float Bt[16][65];   // Bt[kk][dd]
  const int tid = threadIdx.x;
  const int n0 = blockIdx.x * 64;
  const int d0 = blockIdx.y * 64;
  const int p  = blockIdx.z;
  const float* A2  = (p == 0) ? Wqi : (p == 1) ? Wki : (p == 2) ? Wqd : Wkd;  // [t][n]
  const float* Wqk = (p < 2) ? Wiqk : Wdqk;                                    // [d][512]
  const int aoff = (p & 1) * 256;
  const int tx = tid & 15, ty = tid >> 4;

  float acc[4][4];
#pragma unroll
  for (int i = 0; i < 4; ++i)
#pragma unroll
    for (int j = 0; j < 4; ++j) acc[i][j] = 0.f;

  for (int k0 = 0; k0 < 256; k0 += 16) {
    __syncthreads();
    {
      int nn = tid & 63, kr = tid >> 6;
#pragma unroll
      for (int pass = 0; pass < 4; ++pass) {
        int kk = kr + pass * 4;
        At[kk][nn] = A2[(size_t)(k0 + kk) * 256 + n0 + nn];
      }
      int kk = tid & 15, dr = tid >> 4;
#pragma unroll
      for (int pass = 0; pass < 4; ++pass) {
        int dd = dr + pass * 16;
        Bt[kk][dd] = Wqk[(size_t)(d0 + dd) * 512 + aoff + k0 + kk];
      }
    }
    __syncthreads();
#pragma unroll
    for (int kk = 0; kk < 16; ++kk) {
      float a[4], b[4];
#pragma unroll
      for (int i = 0; i < 4; ++i) a[i] = At[kk][ty * 4 + i];
#pragma unroll
      for (int j = 0; j < 4; ++j) b[j] = Bt[kk][tx * 4 + j];
#pragma unroll
      for (int i = 0; i < 4; ++i)
#pragma unroll
        for (int j = 0; j < 4; ++j) acc[i][j] = fmaf(a[i], b[j], acc[i][j]);
    }
  }

#pragma unroll
  for (int i = 0; i < 4; ++i) {
    u16t h[4] = {f2bf(acc[i][0]), f2bf(acc[i][1]), f2bf(acc[i][2]), f2bf(acc[i][3])};
    *(uint2*)(&weffT[((size_t)(p * 256 + n0 + ty * 4 + i)) * 256 + d0 + tx * 4]) =
        *(const uint2*)h;
  }
}

// ---------------------------------------------------------------------------
// Projection GEMM: M=8192 (r=b*512+l), N=1024 (p,h,t), K=256.
__global__ __launch_bounds__(256) void proj_kernel(
    const float* __restrict__ emb, const u16t* __restrict__ weffT,
    const float* __restrict__ bq_inc, const float* __restrict__ bk_inc,
    const float* __restrict__ bq_dec, const float* __restrict__ bk_dec,
    u16t* __restrict__ qk) {
  __shared__ __align__(16) u16t As[128 * 40];
  __shared__ __align__(16) u16t Bs[128 * 40];
  const int t = threadIdx.x;
  const int n0 = blockIdx.x * 128;
  const int r0 = blockIdx.y * 128;
  const int bb = r0 >> 9;
  const int l0 = r0 & 511;
  const int lane = t & 63, wid = t >> 6;
  const int quad = lane >> 4, c15 = lane & 15;
  const int wm = wid >> 1, wn = wid & 1;

  f4v acc[4][4];
#pragma unroll
  for (int i = 0; i < 4; ++i)
#pragma unroll
    for (int j = 0; j < 4; ++j) acc[i][j] = f4v{0.f, 0.f, 0.f, 0.f};

  for (int k0 = 0; k0 < 256; k0 += 32) {
    __syncthreads();
#pragma unroll
    for (int i = 0; i < 2; ++i) {
      int c = t + i * 256;
      int m = c >> 2, off = (c & 3) * 8;
      const float* src = emb + (size_t)((l0 + m) * 16 + bb) * 256 + k0 + off;
      float4 x0 = *(const float4*)src;
      float4 x1 = *(const float4*)(src + 4);
      u16t h[8] = {f2bf(x0.x), f2bf(x0.y), f2bf(x0.z), f2bf(x0.w),
                   f2bf(x1.x), f2bf(x1.y), f2bf(x1.z), f2bf(x1.w)};
      *(uint4*)(&As[m * 40 + off]) = *(const uint4*)h;
      *(uint4*)(&Bs[m * 40 + off]) =
          *(const uint4*)(weffT + (size_t)(n0 + m) * 256 + k0 + off);
    }
    __syncthreads();
    s8v af[4], bf[4];
#pragma unroll
    for (int mi = 0; mi < 4; ++mi)
      af[mi] = *(const s8v*)(&As[(wm * 64 + mi * 16 + c15) * 40 + quad * 8]);
#pragma unroll
    for (int ni = 0; ni < 4; ++ni)
      bf[ni] = *(const s8v*)(&Bs[(wn * 64 + ni * 16 + c15) * 40 + quad * 8]);
#pragma unroll
    for (int mi = 0; mi < 4; ++mi)
#pragma unroll
      for (int ni = 0; ni < 4; ++ni)
        acc[mi][ni] = MFMA16(af[mi], bf[ni], acc[mi][ni], 0, 0, 0);
  }

  const float* biasP[4] = {bq_inc, bk_inc, bq_dec, bk_dec};
#pragma unroll
  for (int ni = 0; ni < 4; ++ni) {
    int n = n0 + wn * 64 + ni * 16 + c15;
    int p = n >> 8, h = (n >> 6) & 3, tt = n & 63, jj = n & 255;
    float bias = biasP[p][jj];
    u16t* dst = qk + (size_t)p * QKN;
#pragma unroll
    for (int mi = 0; mi < 4; ++mi) {
#pragma unroll
      for (int reg = 0; reg < 4; ++reg) {
        int l = l0 + wm * 64 + mi * 16 + quad * 4 + reg;
        dst[((size_t)(bb * 4 + h) * 512 + l) * 64 + tt] = f2bf(acc[mi][ni][reg] + bias);
      }
    }
  }
}

// ---------------------------------------------------------------------------
// Row softmax denominators, wave-independent (R4: no LDS, no barriers).
// Wave w covers (pp,bb,h, l-tile 32); A/B fragments loaded directly from
// global (fragment layout == coalesced dwordx4 pattern on [l][64] rows).
__global__ __launch_bounds__(256) void stats_kernel(
    const u16t* __restrict__ qk, const int* __restrict__ mask, float* __restrict__ invsum) {
  const int t = threadIdx.x;
  const int lane = t & 63, wid = t >> 6;
  const int quad = lane >> 4, c15 = lane & 15;
  const int w = blockIdx.x * 4 + wid;         // [0,2048)
  const int lt = w & 15, cy = w >> 4;         // cy: [0,128)
  const int pp = cy >> 6, bb = (cy >> 2) & 15, h = cy & 3;
  const int l0 = lt * 32;

  const u16t* Q = qk + (size_t)(2 * pp) * QKN + ((size_t)(bb * 4 + h) * 512 + l0) * 64;
  const u16t* K = qk + (size_t)(2 * pp + 1) * QKN + ((size_t)(bb * 4 + h) * 512) * 64;
  const int* mrow = mask + bb * 512;

  s8v a[2][2];
#pragma unroll
  for (int j = 0; j < 2; ++j) {
    a[j][0] = *(const s8v*)(Q + (j * 16 + c15) * 64 + quad * 8);
    a[j][1] = *(const s8v*)(Q + (j * 16 + c15) * 64 + 32 + quad * 8);
  }

  float rs[2][4] = {{0.f, 0.f, 0.f, 0.f}, {0.f, 0.f, 0.f, 0.f}};
  for (int m0 = 0; m0 < 512; m0 += 16) {
    const u16t* Kr = K + (size_t)(m0 + c15) * 64 + quad * 8;
    s8v b0 = *(const s8v*)(Kr);
    s8v b1 = *(const s8v*)(Kr + 32);
    float vm = mrow[m0 + c15] ? 0.f : 1.f;
#pragma unroll
    for (int j = 0; j < 2; ++j) {
      f4v sacc = f4v{0.f, 0.f, 0.f, 0.f};
      sacc = MFMA16(a[j][0], b0, sacc, 0, 0, 0);
      sacc = MFMA16(a[j][1], b1, sacc, 0, 0, 0);
#pragma unroll
      for (int reg = 0; reg < 4; ++reg)
        rs[j][reg] += vm * __expf(sacc[reg] * 0.125f);
    }
  }
#pragma unroll
  for (int j = 0; j < 2; ++j)
#pragma unroll
    for (int reg = 0; reg < 4; ++reg) {
#pragma unroll
      for (int off = 1; off < 16; off <<= 1) rs[j][reg] += __shfl_xor(rs[j][reg], off);
    }
  if (c15 == 0) {
#pragma unroll
    for (int j = 0; j < 2; ++j)
#pragma unroll
      for (int reg = 0; reg < 4; ++reg) {
        int l = l0 + j * 16 + quad * 4 + reg;
        invsum[((size_t)(pp * 16 + bb) * 4 + h) * 512 + l] = 1.0f / rs[j][reg];
      }
  }
}

// ---------------------------------------------------------------------------
// Final fused kernel, wave-independent (R4 restructure: the R3/R4 LDS-staged
// versions were barrier-latency-bound at 47-65 us with all pipes <25% busy).
// Block: l-tile 16 shared by 4 waves; wave: m-tile 32. Q/K fragments loaded
// directly from global (coalesced; L1/L2-hot). One startup barrier only.
__global__ __launch_bounds__(256) void final_kernel(
    const u16t* __restrict__ qk, const int* __restrict__ mask, const float* __restrict__ invsum,
    const int* __restrict__ src_bond, const float* __restrict__ Wc, const float* __restrict__ bc,
    float* __restrict__ out) {
  __shared__ int bondsL[96];   // 16 l x 6
  __shared__ int padls[16];
  const int t = threadIdx.x;
  const int m0 = blockIdx.x * 128;
  const int l0 = blockIdx.y * 16;
  const int bb = blockIdx.z;

  if (t < 96) bondsL[t] = src_bond[(size_t)(bb * 512 + l0 + t / 6) * 6 + (t % 6)];
  else if (t < 112) padls[t - 96] = mask[bb * 512 + l0 + (t - 96)];
  __syncthreads();   // the only barrier

  const int lane = t & 63, wid = t >> 6;
  const int quad = lane >> 4, c15 = lane & 15;
  const int mw = m0 + wid * 32;   // this wave's m-window

  int mval[2];
  mval[0] = mask[bb * 512 + mw + c15];
  mval[1] = mask[bb * 512 + mw + 16 + c15];

  float Wf[16];
#pragma unroll
  for (int i = 0; i < 16; ++i) Wf[i] = Wc[i];

  float dacc[2][4][4];   // [msub][reg][cls]
#pragma unroll
  for (int a = 0; a < 2; ++a)
#pragma unroll
    for (int r = 0; r < 4; ++r)
#pragma unroll
      for (int c = 0; c < 4; ++c) dacc[a][r][c] = 0.f;

  for (int q = 0; q < 8; ++q) {
    const int pp = q >> 2, h = q & 3;
    const u16t* Qb = qk + (size_t)(2 * pp) * QKN + ((size_t)(bb * 4 + h) * 512 + l0) * 64;
    const u16t* Kb = qk + (size_t)(2 * pp + 1) * QKN + ((size_t)(bb * 4 + h) * 512 + mw) * 64;
    s8v a0 = *(const s8v*)(Qb + c15 * 64 + quad * 8);
    s8v a1 = *(const s8v*)(Qb + c15 * 64 + 32 + quad * 8);
    float iv[4];
    const float* ivb = invsum + ((size_t)(pp * 16 + bb) * 4 + h) * 512 + l0 + quad * 4;
#pragma unroll
    for (int reg = 0; reg < 4; ++reg) iv[reg] = ivb[reg];
    const float sgn = pp ? -1.f : 1.f;
#pragma unroll
    for (int ms = 0; ms < 2; ++ms) {
      const u16t* Kr = Kb + (ms * 16 + c15) * 64 + quad * 8;
      s8v b0 = *(const s8v*)(Kr);
      s8v b1 = *(const s8v*)(Kr + 32);
      f4v sacc = f4v{0.f, 0.f, 0.f, 0.f};
      sacc = MFMA16(a0, b0, sacc, 0, 0, 0);
      sacc = MFMA16(a1, b1, sacc, 0, 0, 0);
      const float vm = mval[ms] ? 0.f : sgn;
#pragma unroll
      for (int reg = 0; reg < 4; ++reg) {
        float P = __expf(sacc[reg] * 0.125f) * iv[reg] * vm;
#pragma unroll
        for (int c = 0; c < 4; ++c)
          dacc[ms][reg][c] = fmaf(P, Wf[h * 4 + c], dacc[ms][reg][c]);
      }
    }
  }

  float bcF[4];
#pragma unroll
  for (int c = 0; c < 4; ++c) bcF[c] = bc[c];
  const float lgH = logf(0.7f + 1e-6f);   // one-hot hit
  const float lgM = logf(0.1f + 1e-6f);   // one-hot miss
  const float lgU = logf(0.25f + 1e-6f);  // count >= MAX_DIFF -> uniform

#pragma unroll
  for (int ms = 0; ms < 2; ++ms) {
    int m = mw + ms * 16 + c15;
    bool padm = (mval[ms] == 0);
#pragma unroll
    for (int reg = 0; reg < 4; ++reg) {
      int lloc = quad * 4 + reg;
      int l = l0 + lloc;
      bool pm = padm && (padls[lloc] == 0);
      int cnt = 0;
#pragma unroll
      for (int j = 0; j < 6; ++j) cnt += (bondsL[lloc * 6 + j] == m) ? 1 : 0;
      int cls = (pm && (m != l)) ? cnt : 0;
      float v[4];
#pragma unroll
      for (int c = 0; c < 4; ++c) {
        float lp = (cls >= 4) ? lgU : ((c == cls) ? lgH : lgM);
        float dv = pm ? 4.f * (dacc[ms][reg][c] + bcF[c]) : 0.f;
        v[c] = lp + dv;
      }
      float4 o = make_float4(v[0], v[1], v[2], v[3]);
      *(float4*)(&out[((size_t)(bb * 512 + l) * 512 + m) * 4]) = o;
    }
  }
}

// ---------------------------------------------------------------------------
extern "C" void kernel_launch(void* const* d_in, const int* in_sizes, int n_in,
                              void* d_out, int out_size, void* d_ws, size_t ws_size,
                              hipStream_t stream) {
  (void)in_sizes; (void)n_in; (void)out_size; (void)ws_size;
  const float* emb      = (const float*)d_in[0];
  const int*   src_bond = (const int*)d_in[1];
  const int*   mask_raw = (const int*)d_in[2];
  const float* W_inc_qk = (const float*)d_in[3];
  const float* Wq_inc   = (const float*)d_in[4];
  const float* bq_inc   = (const float*)d_in[5];
  const float* Wk_inc   = (const float*)d_in[6];
  const float* bk_inc   = (const float*)d_in[7];
  const float* W_dec_qk = (const float*)d_in[8];
  const float* Wq_dec   = (const float*)d_in[9];
  const float* bq_dec   = (const float*)d_in[10];
  const float* Wk_dec   = (const float*)d_in[11];
  const float* bk_dec   = (const float*)d_in[12];
  const float* Wc       = (const float*)d_in[13];
  const float* bc       = (const float*)d_in[14];
  float* out = (float*)d_out;

  char* ws = (char*)d_ws;
  int*   wsMask = (int*)ws;                                        // 32 KiB
  u16t*  weffT  = (u16t*)(ws + 32768);                             // 512 KiB
  u16t*  qk     = (u16t*)(ws + 32768 + 524288);                    // 16 MiB (4 bufs)
  float* invsum = (float*)(ws + 32768 + 524288 + 16777216);        // 256 KiB

  hipLaunchKernelGGL(mask_norm,   dim3(32),         dim3(256), 0, stream, mask_raw, wsMask);
  hipLaunchKernelGGL(weff_kernel, dim3(4, 4, 4),    dim3(256), 0, stream,
                     W_inc_qk, Wq_inc, Wk_inc, W_dec_qk, Wq_dec, Wk_dec, weffT);
  hipLaunchKernelGGL(proj_kernel, dim3(8, 64),      dim3(256), 0, stream,
                     emb, weffT, bq_inc, bk_inc, bq_dec, bk_dec, qk);
  hipLaunchKernelGGL(stats_kernel, dim3(512),       dim3(256), 0, stream, qk, wsMask, invsum);
  hipLaunchKernelGGL(final_kernel, dim3(4, 32, 16), dim3(256), 0, stream,
                     qk, wsMask, invsum, src_bond, Wc, bc, out);
}

// Round 6
// 194.923 us; speedup vs baseline: 1.0665x; 1.0665x over previous
//
#include <hip/hip_runtime.h>
#include <stdint.h>

typedef unsigned short u16t;
typedef short s8v __attribute__((ext_vector_type(8)));   // 8 x bf16 (guide §3 frag_ab)
typedef float f4v __attribute__((ext_vector_type(4)));

#define MFMA16 __builtin_amdgcn_mfma_f32_16x16x32_bf16

#define QKN (16*4*512*64)   // elements per Q/K buffer: B*H*L*hd

__device__ __forceinline__ u16t f2bf(float f) {
  unsigned u = __builtin_bit_cast(unsigned, f);
  u += 0x7fffu + ((u >> 16) & 1u);          // RNE
  return (u16t)(u >> 16);
}

// ---------------------------------------------------------------------------
// Canonicalize src_mask into int32[8192].
__global__ __launch_bounds__(256) void mask_norm(const int* __restrict__ raw,
                                                 int* __restrict__ dst) {
  __shared__ int mode;   // 0=int32, 1=bytes, 2=float32
  const int t = threadIdx.x;
  if (t == 0) mode = 0;
  __syncthreads();
  unsigned v0 = (unsigned)raw[t], v1 = (unsigned)raw[t + 256];
  if (v0 == 0x3F800000u || v1 == 0x3F800000u) mode = 2;   // benign race
  __syncthreads();
  if (mode == 0 && (v0 > 1u || v1 > 1u)) mode = 1;
  __syncthreads();
  const int i = blockIdx.x * 256 + t;
  int m;
  if (mode == 2)      m = (((const float*)raw)[i] != 0.0f) ? 1 : 0;
  else if (mode == 1) m = ((const unsigned char*)raw)[i];
  else                m = raw[i];
  dst[i] = m;
}

// ---------------------------------------------------------------------------
// WeffT[p][n][d] = sum_t W2_p[t][n] * Wqk_p[d][aoff+t]   (f32 in, bf16 out).
__global__ __launch_bounds__(256) void weff_kernel(
    const float* __restrict__ Wiqk, const float* __restrict__ Wqi, const float* __restrict__ Wki,
    const float* __restrict__ Wdqk, const float* __restrict__ Wqd, const float* __restrict__ Wkd,
    u16t* __restrict__ weffT) {
  __shared__ float At[16][65];   // At[kk][nn]
  __shared__ float Bt[16][65];   // Bt[kk][dd]
  const int tid = threadIdx.x;
  const int n0 = blockIdx.x * 64;
  const int d0 = blockIdx.y * 64;
  const int p  = blockIdx.z;
  const float* A2  = (p == 0) ? Wqi : (p == 1) ? Wki : (p == 2) ? Wqd : Wkd;  // [t][n]
  const float* Wqk = (p < 2) ? Wiqk : Wdqk;                                    // [d][512]
  const int aoff = (p & 1) * 256;
  const int tx = tid & 15, ty = tid >> 4;

  float acc[4][4];
#pragma unroll
  for (int i = 0; i < 4; ++i)
#pragma unroll
    for (int j = 0; j < 4; ++j) acc[i][j] = 0.f;

  for (int k0 = 0; k0 < 256; k0 += 16) {
    __syncthreads();
    {
      int nn = tid & 63, kr = tid >> 6;
#pragma unroll
      for (int pass = 0; pass < 4; ++pass) {
        int kk = kr + pass * 4;
        At[kk][nn] = A2[(size_t)(k0 + kk) * 256 + n0 + nn];
      }
      int kk = tid & 15, dr = tid >> 4;
#pragma unroll
      for (int pass = 0; pass < 4; ++pass) {
        int dd = dr + pass * 16;
        Bt[kk][dd] = Wqk[(size_t)(d0 + dd) * 512 + aoff + k0 + kk];
      }
    }
    __syncthreads();
#pragma unroll
    for (int kk = 0; kk < 16; ++kk) {
      float a[4], b[4];
#pragma unroll
      for (int i = 0; i < 4; ++i) a[i] = At[kk][ty * 4 + i];
#pragma unroll
      for (int j = 0; j < 4; ++j) b[j] = Bt[kk][tx * 4 + j];
#pragma unroll
      for (int i = 0; i < 4; ++i)
#pragma unroll
        for (int j = 0; j < 4; ++j) acc[i][j] = fmaf(a[i], b[j], acc[i][j]);
    }
  }

#pragma unroll
  for (int i = 0; i < 4; ++i) {
    u16t h[4] = {f2bf(acc[i][0]), f2bf(acc[i][1]), f2bf(acc[i][2]), f2bf(acc[i][3])};
    *(uint2*)(&weffT[((size_t)(p * 256 + n0 + ty * 4 + i)) * 256 + d0 + tx * 4]) =
        *(const uint2*)h;
  }
}

// ---------------------------------------------------------------------------
// Projection GEMM: M=8192 (r=b*512+l), N=1024 (p,h,t), K=256.
__global__ __launch_bounds__(256) void proj_kernel(
    const float* __restrict__ emb, const u16t* __restrict__ weffT,
    const float* __restrict__ bq_inc, const float* __restrict__ bk_inc,
    const float* __restrict__ bq_dec, const float* __restrict__ bk_dec,
    u16t* __restrict__ qk) {
  __shared__ __align__(16) u16t As[128 * 40];
  __shared__ __align__(16) u16t Bs[128 * 40];
  const int t = threadIdx.x;
  const int n0 = blockIdx.x * 128;
  const int r0 = blockIdx.y * 128;
  const int bb = r0 >> 9;
  const int l0 = r0 & 511;
  const int lane = t & 63, wid = t >> 6;
  const int quad = lane >> 4, c15 = lane & 15;
  const int wm = wid >> 1, wn = wid & 1;

  f4v acc[4][4];
#pragma unroll
  for (int i = 0; i < 4; ++i)
#pragma unroll
    for (int j = 0; j < 4; ++j) acc[i][j] = f4v{0.f, 0.f, 0.f, 0.f};

  for (int k0 = 0; k0 < 256; k0 += 32) {
    __syncthreads();
#pragma unroll
    for (int i = 0; i < 2; ++i) {
      int c = t + i * 256;
      int m = c >> 2, off = (c & 3) * 8;
      const float* src = emb + (size_t)((l0 + m) * 16 + bb) * 256 + k0 + off;
      float4 x0 = *(const float4*)src;
      float4 x1 = *(const float4*)(src + 4);
      u16t h[8] = {f2bf(x0.x), f2bf(x0.y), f2bf(x0.z), f2bf(x0.w),
                   f2bf(x1.x), f2bf(x1.y), f2bf(x1.z), f2bf(x1.w)};
      *(uint4*)(&As[m * 40 + off]) = *(const uint4*)h;
      *(uint4*)(&Bs[m * 40 + off]) =
          *(const uint4*)(weffT + (size_t)(n0 + m) * 256 + k0 + off);
    }
    __syncthreads();
    s8v af[4], bf[4];
#pragma unroll
    for (int mi = 0; mi < 4; ++mi)
      af[mi] = *(const s8v*)(&As[(wm * 64 + mi * 16 + c15) * 40 + quad * 8]);
#pragma unroll
    for (int ni = 0; ni < 4; ++ni)
      bf[ni] = *(const s8v*)(&Bs[(wn * 64 + ni * 16 + c15) * 40 + quad * 8]);
#pragma unroll
    for (int mi = 0; mi < 4; ++mi)
#pragma unroll
      for (int ni = 0; ni < 4; ++ni)
        acc[mi][ni] = MFMA16(af[mi], bf[ni], acc[mi][ni], 0, 0, 0);
  }

  const float* biasP[4] = {bq_inc, bk_inc, bq_dec, bk_dec};
#pragma unroll
  for (int ni = 0; ni < 4; ++ni) {
    int n = n0 + wn * 64 + ni * 16 + c15;
    int p = n >> 8, h = (n >> 6) & 3, tt = n & 63, jj = n & 255;
    float bias = biasP[p][jj];
    u16t* dst = qk + (size_t)p * QKN;
#pragma unroll
    for (int mi = 0; mi < 4; ++mi) {
#pragma unroll
      for (int reg = 0; reg < 4; ++reg) {
        int l = l0 + wm * 64 + mi * 16 + quad * 4 + reg;
        dst[((size_t)(bb * 4 + h) * 512 + l) * 64 + tt] = f2bf(acc[mi][ni][reg] + bias);
      }
    }
  }
}

// ---------------------------------------------------------------------------
// Fused softmax + diff + bond kernel (R5 restructure: stats folded in).
// Block = 512 threads (8 waves) covers (bb, l-tile 16) x ALL 512 m.
// Wave w owns m-window [w*64, w*64+64) (4 sub-tiles of 16).
// Per (path,head) combo: each wave computes exp(QK/8) for its 32 (l,m)
// points (kept in regs), in-wave + LDS tree-reduce gives the row sum,
// then dacc += sign * e * inv * Wc[h]. One barrier per combo (red dbuf).
// Grid is XCD-swizzled 1D: id = tile*8 + (bb>>1) so each XCD sees 2 bbs
// (2 MB K working set fits per-XCD 4 MB L2).
__global__ __launch_bounds__(512) void fused_kernel(
    const u16t* __restrict__ qk, const int* __restrict__ mask,
    const int* __restrict__ src_bond, const float* __restrict__ Wc,
    const float* __restrict__ bc, float* __restrict__ out) {
  __shared__ int bondsL[96];      // 16 l x 6
  __shared__ int padls[16];
  __shared__ float red[2][8][16]; // [dbuf][wave][l]
  const int t = threadIdx.x;
  const int id = blockIdx.x;
  const int xcd = id & 7, tile = id >> 3;
  const int lt = tile & 31, half = tile >> 5;
  const int bb = xcd * 2 + half;
  const int l0 = lt * 16;

  if (t < 96) bondsL[t] = src_bond[(size_t)(bb * 512 + l0 + t / 6) * 6 + (t % 6)];
  else if (t < 112) padls[t - 96] = mask[bb * 512 + l0 + (t - 96)];

  const int lane = t & 63, w = t >> 6;   // w in [0,8)
  const int quad = lane >> 4, c15 = lane & 15;
  const int mw = w * 64;

  float vmask[4];
#pragma unroll
  for (int ms = 0; ms < 4; ++ms)
    vmask[ms] = mask[bb * 512 + mw + ms * 16 + c15] ? 0.f : 1.f;

  float dacc[4][4][4];   // [ms][reg][cls]
#pragma unroll
  for (int a = 0; a < 4; ++a)
#pragma unroll
    for (int r = 0; r < 4; ++r)
#pragma unroll
      for (int c = 0; c < 4; ++c) dacc[a][r][c] = 0.f;

  __syncthreads();   // bondsL/padls visible

  for (int q = 0; q < 8; ++q) {
    const int pp = q >> 2, h = q & 3;
    const u16t* Qb = qk + (size_t)(2 * pp) * QKN + ((size_t)(bb * 4 + h) * 512 + l0) * 64;
    const u16t* Kb = qk + (size_t)(2 * pp + 1) * QKN + ((size_t)(bb * 4 + h) * 512 + mw) * 64;
    s8v a0 = *(const s8v*)(Qb + c15 * 64 + quad * 8);
    s8v a1 = *(const s8v*)(Qb + c15 * 64 + 32 + quad * 8);

    float e[4][4];
    float part[4] = {0.f, 0.f, 0.f, 0.f};
#pragma unroll
    for (int ms = 0; ms < 4; ++ms) {
      const u16t* Kr = Kb + (ms * 16 + c15) * 64 + quad * 8;
      s8v b0 = *(const s8v*)(Kr);
      s8v b1 = *(const s8v*)(Kr + 32);
      f4v sacc = f4v{0.f, 0.f, 0.f, 0.f};
      sacc = MFMA16(a0, b0, sacc, 0, 0, 0);
      sacc = MFMA16(a1, b1, sacc, 0, 0, 0);
#pragma unroll
      for (int r = 0; r < 4; ++r) {
        float ev = vmask[ms] * __expf(sacc[r] * 0.125f);
        e[ms][r] = ev;
        part[r] += ev;
      }
    }
    // in-wave reduce over the 16 m-lanes of each quad
#pragma unroll
    for (int r = 0; r < 4; ++r) {
#pragma unroll
      for (int off = 1; off < 16; off <<= 1) part[r] += __shfl_xor(part[r], off);
    }
    const int buf = q & 1;
    if (c15 == 0) {
#pragma unroll
      for (int r = 0; r < 4; ++r) red[buf][w][quad * 4 + r] = part[r];
    }
    __syncthreads();   // the only barrier per combo (dbuf makes it safe)
    float inv[4];
#pragma unroll
    for (int r = 0; r < 4; ++r) {
      float tot = 0.f;
#pragma unroll
      for (int ww = 0; ww < 8; ++ww) tot += red[buf][ww][quad * 4 + r];
      inv[r] = 1.0f / tot;
    }
    const float sgn = pp ? -1.f : 1.f;
#pragma unroll
    for (int ms = 0; ms < 4; ++ms)
#pragma unroll
      for (int r = 0; r < 4; ++r) {
        float P = e[ms][r] * inv[r] * sgn;
#pragma unroll
        for (int c = 0; c < 4; ++c)
          dacc[ms][r][c] = fmaf(P, Wc[h * 4 + c], dacc[ms][r][c]);
      }
  }

  float bcF[4];
#pragma unroll
  for (int c = 0; c < 4; ++c) bcF[c] = bc[c];
  const float lgH = logf(0.7f + 1e-6f);   // one-hot hit
  const float lgM = logf(0.1f + 1e-6f);   // one-hot miss
  const float lgU = logf(0.25f + 1e-6f);  // count >= MAX_DIFF -> uniform

#pragma unroll
  for (int ms = 0; ms < 4; ++ms) {
    int m = mw + ms * 16 + c15;
    bool padm = (vmask[ms] != 0.f);
#pragma unroll
    for (int r = 0; r < 4; ++r) {
      int lloc = quad * 4 + r;
      int l = l0 + lloc;
      bool pm = padm && (padls[lloc] == 0);
      int cnt = 0;
#pragma unroll
      for (int j = 0; j < 6; ++j) cnt += (bondsL[lloc * 6 + j] == m) ? 1 : 0;
      int cls = (pm && (m != l)) ? cnt : 0;
      float v[4];
#pragma unroll
      for (int c = 0; c < 4; ++c) {
        float lp = (cls >= 4) ? lgU : ((c == cls) ? lgH : lgM);
        float dv = pm ? 4.f * (dacc[ms][r][c] + bcF[c]) : 0.f;
        v[c] = lp + dv;
      }
      float4 o = make_float4(v[0], v[1], v[2], v[3]);
      *(float4*)(&out[((size_t)(bb * 512 + l) * 512 + m) * 4]) = o;
    }
  }
}

// ---------------------------------------------------------------------------
extern "C" void kernel_launch(void* const* d_in, const int* in_sizes, int n_in,
                              void* d_out, int out_size, void* d_ws, size_t ws_size,
                              hipStream_t stream) {
  (void)in_sizes; (void)n_in; (void)out_size; (void)ws_size;
  const float* emb      = (const float*)d_in[0];
  const int*   src_bond = (const int*)d_in[1];
  const int*   mask_raw = (const int*)d_in[2];
  const float* W_inc_qk = (const float*)d_in[3];
  const float* Wq_inc   = (const float*)d_in[4];
  const float* bq_inc   = (const float*)d_in[5];
  const float* Wk_inc   = (const float*)d_in[6];
  const float* bk_inc   = (const float*)d_in[7];
  const float* W_dec_qk = (const float*)d_in[8];
  const float* Wq_dec   = (const float*)d_in[9];
  const float* bq_dec   = (const float*)d_in[10];
  const float* Wk_dec   = (const float*)d_in[11];
  const float* bk_dec   = (const float*)d_in[12];
  const float* Wc       = (const float*)d_in[13];
  const float* bc       = (const float*)d_in[14];
  float* out = (float*)d_out;

  char* ws = (char*)d_ws;
  int*   wsMask = (int*)ws;                                        // 32 KiB
  u16t*  weffT  = (u16t*)(ws + 32768);                             // 512 KiB
  u16t*  qk     = (u16t*)(ws + 32768 + 524288);                    // 16 MiB (4 bufs)

  hipLaunchKernelGGL(mask_norm,   dim3(32),      dim3(256), 0, stream, mask_raw, wsMask);
  hipLaunchKernelGGL(weff_kernel, dim3(4, 4, 4), dim3(256), 0, stream,
                     W_inc_qk, Wq_inc, Wk_inc, W_dec_qk, Wq_dec, Wk_dec, weffT);
  hipLaunchKernelGGL(proj_kernel, dim3(8, 64),   dim3(256), 0, stream,
                     emb, weffT, bq_inc, bk_inc, bq_dec, bk_dec, qk);
  hipLaunchKernelGGL(fused_kernel, dim3(512),    dim3(512), 0, stream,
                     qk, wsMask, src_bond, Wc, bc, out);
}

// Round 7
// 182.598 us; speedup vs baseline: 1.1385x; 1.0675x over previous
//
#include <hip/hip_runtime.h>
#include <stdint.h>

typedef unsigned short u16t;
typedef short s8v __attribute__((ext_vector_type(8)));   // 8 x bf16 (guide §3 frag_ab)
typedef float f4v __attribute__((ext_vector_type(4)));

#define MFMA16 __builtin_amdgcn_mfma_f32_16x16x32_bf16

// qk rows padded 64 -> 72 elems (144 B): keeps 16B alignment, breaks the
// 32-bank alignment (2-way aliasing only, free per m136).
#define QKROW 72
#define QKN72 (16*4*512*QKROW)   // elements per path buffer

__device__ __forceinline__ u16t f2bf(float f) {
  unsigned u = __builtin_bit_cast(unsigned, f);
  u += 0x7fffu + ((u >> 16) & 1u);          // RNE
  return (u16t)(u >> 16);
}

// ---------------------------------------------------------------------------
// Canonicalize src_mask into int32[8192].
__global__ __launch_bounds__(256) void mask_norm(const int* __restrict__ raw,
                                                 int* __restrict__ dst) {
  __shared__ int mode;   // 0=int32, 1=bytes, 2=float32
  const int t = threadIdx.x;
  if (t == 0) mode = 0;
  __syncthreads();
  unsigned v0 = (unsigned)raw[t], v1 = (unsigned)raw[t + 256];
  if (v0 == 0x3F800000u || v1 == 0x3F800000u) mode = 2;   // benign race
  __syncthreads();
  if (mode == 0 && (v0 > 1u || v1 > 1u)) mode = 1;
  __syncthreads();
  const int i = blockIdx.x * 256 + t;
  int m;
  if (mode == 2)      m = (((const float*)raw)[i] != 0.0f) ? 1 : 0;
  else if (mode == 1) m = ((const unsigned char*)raw)[i];
  else                m = raw[i];
  dst[i] = m;
}

// ---------------------------------------------------------------------------
// WeffT[p][n][d] = sum_t W2_p[t][n] * Wqk_p[d][aoff+t]   (f32 in, bf16 out).
__global__ __launch_bounds__(256) void weff_kernel(
    const float* __restrict__ Wiqk, const float* __restrict__ Wqi, const float* __restrict__ Wki,
    const float* __restrict__ Wdqk, const float* __restrict__ Wqd, const float* __restrict__ Wkd,
    u16t* __restrict__ weffT) {
  __shared__ float At[16][65];   // At[kk][nn]
  __shared__ float Bt[16][65];   // Bt[kk][dd]
  const int tid = threadIdx.x;
  const int n0 = blockIdx.x * 64;
  const int d0 = blockIdx.y * 64;
  const int p  = blockIdx.z;
  const float* A2  = (p == 0) ? Wqi : (p == 1) ? Wki : (p == 2) ? Wqd : Wkd;  // [t][n]
  const float* Wqk = (p < 2) ? Wiqk : Wdqk;                                    // [d][512]
  const int aoff = (p & 1) * 256;
  const int tx = tid & 15, ty = tid >> 4;

  float acc[4][4];
#pragma unroll
  for (int i = 0; i < 4; ++i)
#pragma unroll
    for (int j = 0; j < 4; ++j) acc[i][j] = 0.f;

  for (int k0 = 0; k0 < 256; k0 += 16) {
    __syncthreads();
    {
      int nn = tid & 63, kr = tid >> 6;
#pragma unroll
      for (int pass = 0; pass < 4; ++pass) {
        int kk = kr + pass * 4;
        At[kk][nn] = A2[(size_t)(k0 + kk) * 256 + n0 + nn];
      }
      int kk = tid & 15, dr = tid >> 4;
#pragma unroll
      for (int pass = 0; pass < 4; ++pass) {
        int dd = dr + pass * 16;
        Bt[kk][dd] = Wqk[(size_t)(d0 + dd) * 512 + aoff + k0 + kk];
      }
    }
    __syncthreads();
#pragma unroll
    for (int kk = 0; kk < 16; ++kk) {
      float a[4], b[4];
#pragma unroll
      for (int i = 0; i < 4; ++i) a[i] = At[kk][ty * 4 + i];
#pragma unroll
      for (int j = 0; j < 4; ++j) b[j] = Bt[kk][tx * 4 + j];
#pragma unroll
      for (int i = 0; i < 4; ++i)
#pragma unroll
        for (int j = 0; j < 4; ++j) acc[i][j] = fmaf(a[i], b[j], acc[i][j]);
    }
  }

#pragma unroll
  for (int i = 0; i < 4; ++i) {
    u16t h[4] = {f2bf(acc[i][0]), f2bf(acc[i][1]), f2bf(acc[i][2]), f2bf(acc[i][3])};
    *(uint2*)(&weffT[((size_t)(p * 256 + n0 + ty * 4 + i)) * 256 + d0 + tx * 4]) =
        *(const uint2*)h;
  }
}

// ---------------------------------------------------------------------------
// Projection GEMM: M=8192 (r=b*512+l), N=1024 (p,h,t), K=256.
// Out -> qk[p][b][h][l][QKROW] (bf16, padded rows) + bias.
__global__ __launch_bounds__(256) void proj_kernel(
    const float* __restrict__ emb, const u16t* __restrict__ weffT,
    const float* __restrict__ bq_inc, const float* __restrict__ bk_inc,
    const float* __restrict__ bq_dec, const float* __restrict__ bk_dec,
    u16t* __restrict__ qk) {
  __shared__ __align__(16) u16t As[128 * 40];
  __shared__ __align__(16) u16t Bs[128 * 40];
  const int t = threadIdx.x;
  const int n0 = blockIdx.x * 128;
  const int r0 = blockIdx.y * 128;
  const int bb = r0 >> 9;
  const int l0 = r0 & 511;
  const int lane = t & 63, wid = t >> 6;
  const int quad = lane >> 4, c15 = lane & 15;
  const int wm = wid >> 1, wn = wid & 1;

  f4v acc[4][4];
#pragma unroll
  for (int i = 0; i < 4; ++i)
#pragma unroll
    for (int j = 0; j < 4; ++j) acc[i][j] = f4v{0.f, 0.f, 0.f, 0.f};

  for (int k0 = 0; k0 < 256; k0 += 32) {
    __syncthreads();
#pragma unroll
    for (int i = 0; i < 2; ++i) {
      int c = t + i * 256;
      int m = c >> 2, off = (c & 3) * 8;
      const float* src = emb + (size_t)((l0 + m) * 16 + bb) * 256 + k0 + off;
      float4 x0 = *(const float4*)src;
      float4 x1 = *(const float4*)(src + 4);
      u16t h[8] = {f2bf(x0.x), f2bf(x0.y), f2bf(x0.z), f2bf(x0.w),
                   f2bf(x1.x), f2bf(x1.y), f2bf(x1.z), f2bf(x1.w)};
      *(uint4*)(&As[m * 40 + off]) = *(const uint4*)h;
      *(uint4*)(&Bs[m * 40 + off]) =
          *(const uint4*)(weffT + (size_t)(n0 + m) * 256 + k0 + off);
    }
    __syncthreads();
    s8v af[4], bf[4];
#pragma unroll
    for (int mi = 0; mi < 4; ++mi)
      af[mi] = *(const s8v*)(&As[(wm * 64 + mi * 16 + c15) * 40 + quad * 8]);
#pragma unroll
    for (int ni = 0; ni < 4; ++ni)
      bf[ni] = *(const s8v*)(&Bs[(wn * 64 + ni * 16 + c15) * 40 + quad * 8]);
#pragma unroll
    for (int mi = 0; mi < 4; ++mi)
#pragma unroll
      for (int ni = 0; ni < 4; ++ni)
        acc[mi][ni] = MFMA16(af[mi], bf[ni], acc[mi][ni], 0, 0, 0);
  }

  const float* biasP[4] = {bq_inc, bk_inc, bq_dec, bk_dec};
#pragma unroll
  for (int ni = 0; ni < 4; ++ni) {
    int n = n0 + wn * 64 + ni * 16 + c15;
    int p = n >> 8, h = (n >> 6) & 3, tt = n & 63, jj = n & 255;
    float bias = biasP[p][jj];
    u16t* dst = qk + (size_t)p * QKN72;
#pragma unroll
    for (int mi = 0; mi < 4; ++mi) {
#pragma unroll
      for (int reg = 0; reg < 4; ++reg) {
        int l = l0 + wm * 64 + mi * 16 + quad * 4 + reg;
        dst[((size_t)(bb * 4 + h) * 512 + l) * QKROW + tt] = f2bf(acc[mi][ni][reg] + bias);
      }
    }
  }
}

// ---------------------------------------------------------------------------
// Row softmax denominators. Block = 256 thr (4 waves), l-tile 128 (wave
// owns 32 l-rows across ALL m -> wave-local row sum, no cross-wave reduce).
// XCD-swizzled; padded LDS rows -> conflict-free fragment reads.
__global__ __launch_bounds__(256) void stats_kernel(
    const u16t* __restrict__ qk, const int* __restrict__ mask, float* __restrict__ invsum) {
  __shared__ __align__(16) u16t Qs[128 * QKROW];
  __shared__ __align__(16) u16t Ks[128 * QKROW];
  __shared__ int mrow[512];
  const int t = threadIdx.x;
  const int id = blockIdx.x;               // 512 blocks
  const int xcd = id & 7, r1 = id >> 3;    // r1: [0,64)
  const int bb = xcd * 2 + (r1 & 1);
  const int rem = r1 >> 1;                 // [0,32)
  const int pp = rem >> 4, h = (rem >> 2) & 3, lt = rem & 3;
  const int l0 = lt * 128;

  const u16t* Q = qk + (size_t)(2 * pp) * QKN72 + ((size_t)(bb * 4 + h) * 512 + l0) * QKROW;
  const u16t* K = qk + (size_t)(2 * pp + 1) * QKN72 + ((size_t)(bb * 4 + h) * 512) * QKROW;

  // stage Q tile (128 x 144 B = 1152 uint4) + mask row
  for (int i = t; i < 1152; i += 256)
    *(uint4*)(&Qs[i * 8]) = *(const uint4*)(Q + i * 8);
  mrow[t] = mask[bb * 512 + t];
  mrow[t + 256] = mask[bb * 512 + t + 256];

  const int lane = t & 63, wid = t >> 6;
  const int quad = lane >> 4, c15 = lane & 15;

  float rs[2][4] = {{0.f, 0.f, 0.f, 0.f}, {0.f, 0.f, 0.f, 0.f}};
  for (int m0 = 0; m0 < 512; m0 += 128) {
    __syncthreads();   // Ks free (and Q/mrow visible on first iter)
    for (int i = t; i < 1152; i += 256)
      *(uint4*)(&Ks[i * 8]) = *(const uint4*)(K + (size_t)m0 * QKROW + i * 8);
    __syncthreads();
    s8v a[2][2];
#pragma unroll
    for (int j = 0; j < 2; ++j) {
      int row = wid * 32 + j * 16 + c15;
      a[j][0] = *(const s8v*)(&Qs[row * QKROW + quad * 8]);
      a[j][1] = *(const s8v*)(&Qs[row * QKROW + 32 + quad * 8]);
    }
#pragma unroll
    for (int nt = 0; nt < 8; ++nt) {
      int mloc = nt * 16 + c15;
      s8v b0 = *(const s8v*)(&Ks[mloc * QKROW + quad * 8]);
      s8v b1 = *(const s8v*)(&Ks[mloc * QKROW + 32 + quad * 8]);
      float vm = mrow[m0 + mloc] ? 0.f : 1.f;
#pragma unroll
      for (int j = 0; j < 2; ++j) {
        f4v sacc = f4v{0.f, 0.f, 0.f, 0.f};
        sacc = MFMA16(a[j][0], b0, sacc, 0, 0, 0);
        sacc = MFMA16(a[j][1], b1, sacc, 0, 0, 0);
#pragma unroll
        for (int reg = 0; reg < 4; ++reg)
          rs[j][reg] += vm * __expf(sacc[reg] * 0.125f);
      }
    }
  }
#pragma unroll
  for (int j = 0; j < 2; ++j)
#pragma unroll
    for (int reg = 0; reg < 4; ++reg) {
#pragma unroll
      for (int off = 1; off < 16; off <<= 1) rs[j][reg] += __shfl_xor(rs[j][reg], off);
    }
  if (c15 == 0) {
#pragma unroll
    for (int j = 0; j < 2; ++j)
#pragma unroll
      for (int reg = 0; reg < 4; ++reg) {
        int l = l0 + wid * 32 + j * 16 + quad * 4 + reg;
        invsum[((size_t)(pp * 16 + bb) * 4 + h) * 512 + l] = 1.0f / rs[j][reg];
      }
  }
}

// ---------------------------------------------------------------------------
// Final fused kernel, R3 geometry (the best-measured: l16 x m128, 4 waves,
// grid 2048 -> ~6 blocks/CU) + XCD swizzle + padded conflict-free LDS.
__global__ __launch_bounds__(256) void final_kernel(
    const u16t* __restrict__ qk, const int* __restrict__ mask, const float* __restrict__ invsum,
    const int* __restrict__ src_bond, const float* __restrict__ Wc, const float* __restrict__ bc,
    float* __restrict__ out) {
  __shared__ __align__(16) u16t Ks[128 * QKROW];
  __shared__ int bondsL[96];   // 16 l x 6
  __shared__ int padls[16];
  const int t = threadIdx.x;
  const int id = blockIdx.x;               // 2048 blocks
  const int xcd = id & 7, r1 = id >> 3;    // r1: [0,256)
  const int bb = xcd * 2 + (r1 & 1);
  const int tile = r1 >> 1;                // [0,128)
  const int mt = tile & 3, lt = tile >> 2;
  const int m0 = mt * 128;
  const int l0 = lt * 16;

  if (t < 96) bondsL[t] = src_bond[(size_t)(bb * 512 + l0 + t / 6) * 6 + (t % 6)];
  else if (t < 112) padls[t - 96] = mask[bb * 512 + l0 + (t - 96)];

  const int lane = t & 63, wid = t >> 6;
  const int quad = lane >> 4, c15 = lane & 15;

  int mval[2];
  mval[0] = mask[bb * 512 + m0 + wid * 32 + c15];
  mval[1] = mask[bb * 512 + m0 + wid * 32 + 16 + c15];

  float Wf[16];
#pragma unroll
  for (int i = 0; i < 16; ++i) Wf[i] = Wc[i];

  float dacc[2][4][4];   // [msub][reg][cls]
#pragma unroll
  for (int a = 0; a < 2; ++a)
#pragma unroll
    for (int r = 0; r < 4; ++r)
#pragma unroll
      for (int c = 0; c < 4; ++c) dacc[a][r][c] = 0.f;

  for (int q = 0; q < 8; ++q) {
    const int pp = q >> 2, h = q & 3;
    __syncthreads();   // Ks free (first iter: bonds/padls visible)
    const u16t* Kb = qk + (size_t)(2 * pp + 1) * QKN72 + ((size_t)(bb * 4 + h) * 512 + m0) * QKROW;
    for (int i = t; i < 1152; i += 256)
      *(uint4*)(&Ks[i * 8]) = *(const uint4*)(Kb + i * 8);
    const u16t* Qb = qk + (size_t)(2 * pp) * QKN72 + ((size_t)(bb * 4 + h) * 512 + l0) * QKROW;
    s8v a0 = *(const s8v*)(Qb + c15 * QKROW + quad * 8);
    s8v a1 = *(const s8v*)(Qb + c15 * QKROW + 32 + quad * 8);
    float iv[4];
    const float* ivb = invsum + ((size_t)(pp * 16 + bb) * 4 + h) * 512 + l0 + quad * 4;
#pragma unroll
    for (int reg = 0; reg < 4; ++reg) iv[reg] = ivb[reg];
    __syncthreads();
    const float sgn = pp ? -1.f : 1.f;
#pragma unroll
    for (int ms = 0; ms < 2; ++ms) {
      int mloc = wid * 32 + ms * 16 + c15;
      s8v b0 = *(const s8v*)(&Ks[mloc * QKROW + quad * 8]);
      s8v b1 = *(const s8v*)(&Ks[mloc * QKROW + 32 + quad * 8]);
      f4v sacc = f4v{0.f, 0.f, 0.f, 0.f};
      sacc = MFMA16(a0, b0, sacc, 0, 0, 0);
      sacc = MFMA16(a1, b1, sacc, 0, 0, 0);
      const float vm = mval[ms] ? 0.f : sgn;
#pragma unroll
      for (int reg = 0; reg < 4; ++reg) {
        float P = __expf(sacc[reg] * 0.125f) * iv[reg] * vm;
#pragma unroll
        for (int c = 0; c < 4; ++c)
          dacc[ms][reg][c] = fmaf(P, Wf[h * 4 + c], dacc[ms][reg][c]);
      }
    }
  }

  float bcF[4];
#pragma unroll
  for (int c = 0; c < 4; ++c) bcF[c] = bc[c];
  const float lgH = logf(0.7f + 1e-6f);   // one-hot hit
  const float lgM = logf(0.1f + 1e-6f);   // one-hot miss
  const float lgU = logf(0.25f + 1e-6f);  // count >= MAX_DIFF -> uniform

#pragma unroll
  for (int ms = 0; ms < 2; ++ms) {
    int m = m0 + wid * 32 + ms * 16 + c15;
    bool padm = (mval[ms] == 0);
#pragma unroll
    for (int reg = 0; reg < 4; ++reg) {
      int lloc = quad * 4 + reg;
      int l = l0 + lloc;
      bool pm = padm && (padls[lloc] == 0);
      int cnt = 0;
#pragma unroll
      for (int j = 0; j < 6; ++j) cnt += (bondsL[lloc * 6 + j] == m) ? 1 : 0;
      int cls = (pm && (m != l)) ? cnt : 0;
      float v[4];
#pragma unroll
      for (int c = 0; c < 4; ++c) {
        float lp = (cls >= 4) ? lgU : ((c == cls) ? lgH : lgM);
        float dv = pm ? 4.f * (dacc[ms][reg][c] + bcF[c]) : 0.f;
        v[c] = lp + dv;
      }
      float4 o = make_float4(v[0], v[1], v[2], v[3]);
      *(float4*)(&out[((size_t)(bb * 512 + l) * 512 + m) * 4]) = o;
    }
  }
}

// ---------------------------------------------------------------------------
extern "C" void kernel_launch(void* const* d_in, const int* in_sizes, int n_in,
                              void* d_out, int out_size, void* d_ws, size_t ws_size,
                              hipStream_t stream) {
  (void)in_sizes; (void)n_in; (void)out_size; (void)ws_size;
  const float* emb      = (const float*)d_in[0];
  const int*   src_bond = (const int*)d_in[1];
  const int*   mask_raw = (const int*)d_in[2];
  const float* W_inc_qk = (const float*)d_in[3];
  const float* Wq_inc   = (const float*)d_in[4];
  const float* bq_inc   = (const float*)d_in[5];
  const float* Wk_inc   = (const float*)d_in[6];
  const float* bk_inc   = (const float*)d_in[7];
  const float* W_dec_qk = (const float*)d_in[8];
  const float* Wq_dec   = (const float*)d_in[9];
  const float* bq_dec   = (const float*)d_in[10];
  const float* Wk_dec   = (const float*)d_in[11];
  const float* bk_dec   = (const float*)d_in[12];
  const float* Wc       = (const float*)d_in[13];
  const float* bc       = (const float*)d_in[14];
  float* out = (float*)d_out;

  char* ws = (char*)d_ws;
  int*   wsMask = (int*)ws;                                  // 32 KiB
  u16t*  weffT  = (u16t*)(ws + 32768);                       // 512 KiB
  u16t*  qk     = (u16t*)(ws + 557056);                      // 4 x 4.72 MiB (padded)
  float* invsum = (float*)(ws + 557056 + (size_t)4 * QKN72 * 2);

  hipLaunchKernelGGL(mask_norm,   dim3(32),      dim3(256), 0, stream, mask_raw, wsMask);
  hipLaunchKernelGGL(weff_kernel, dim3(4, 4, 4), dim3(256), 0, stream,
                     W_inc_qk, Wq_inc, Wk_inc, W_dec_qk, Wq_dec, Wk_dec, weffT);
  hipLaunchKernelGGL(proj_kernel, dim3(8, 64),   dim3(256), 0, stream,
                     emb, weffT, bq_inc, bk_inc, bq_dec, bk_dec, qk);
  hipLaunchKernelGGL(stats_kernel, dim3(512),    dim3(256), 0, stream, qk, wsMask, invsum);
  hipLaunchKernelGGL(final_kernel, dim3(2048),   dim3(256), 0, stream,
                     qk, wsMask, invsum, src_bond, Wc, bc, out);
}

// Round 8
// 182.258 us; speedup vs baseline: 1.1407x; 1.0019x over previous
//
#include <hip/hip_runtime.h>
#include <stdint.h>

typedef unsigned short u16t;
typedef short s8v __attribute__((ext_vector_type(8)));   // 8 x bf16 (guide §3 frag_ab)
typedef float f4v __attribute__((ext_vector_type(4)));

#define MFMA16 __builtin_amdgcn_mfma_f32_16x16x32_bf16

// qk rows padded 64 -> 72 elems (144 B): keeps 16B alignment, breaks the
// 32-bank alignment (2-way aliasing only, free per m136).
#define QKROW 72
#define QKN72 (16*4*512*QKROW)   // elements per path buffer

__device__ __forceinline__ u16t f2bf(float f) {
  unsigned u = __builtin_bit_cast(unsigned, f);
  u += 0x7fffu + ((u >> 16) & 1u);          // RNE
  return (u16t)(u >> 16);
}

// ---------------------------------------------------------------------------
// Canonicalize src_mask into int32[8192].
__global__ __launch_bounds__(256) void mask_norm(const int* __restrict__ raw,
                                                 int* __restrict__ dst) {
  __shared__ int mode;   // 0=int32, 1=bytes, 2=float32
  const int t = threadIdx.x;
  if (t == 0) mode = 0;
  __syncthreads();
  unsigned v0 = (unsigned)raw[t], v1 = (unsigned)raw[t + 256];
  if (v0 == 0x3F800000u || v1 == 0x3F800000u) mode = 2;   // benign race
  __syncthreads();
  if (mode == 0 && (v0 > 1u || v1 > 1u)) mode = 1;
  __syncthreads();
  const int i = blockIdx.x * 256 + t;
  int m;
  if (mode == 2)      m = (((const float*)raw)[i] != 0.0f) ? 1 : 0;
  else if (mode == 1) m = ((const unsigned char*)raw)[i];
  else                m = raw[i];
  dst[i] = m;
}

// ---------------------------------------------------------------------------
// emb [l][b][d] f32  ->  Abf [b*512+l][d] bf16. Coalesced read (32 lanes
// cover one 1 KB row) and write. (R7 fix: proj's direct f32 A-read strided
// 16 KB between tile rows, 4x line overfetch — weff-style pathology.)
__global__ __launch_bounds__(256) void prep_kernel(const float* __restrict__ emb,
                                                   u16t* __restrict__ Abf) {
  const int gi = blockIdx.x * 256 + threadIdx.x;   // 8192*32 chunks
  const int d8 = gi & 31, row = gi >> 5;           // row = b*512+l
  const int l = row & 511, b = row >> 9;
  const float* src = emb + ((size_t)(l * 16 + b) * 256 + d8 * 8);
  float4 x0 = *(const float4*)src;
  float4 x1 = *(const float4*)(src + 4);
  u16t h[8] = {f2bf(x0.x), f2bf(x0.y), f2bf(x0.z), f2bf(x0.w),
               f2bf(x1.x), f2bf(x1.y), f2bf(x1.z), f2bf(x1.w)};
  *(uint4*)(&Abf[(size_t)row * 256 + d8 * 8]) = *(const uint4*)h;
}

// ---------------------------------------------------------------------------
// WeffT[p][n][d] = sum_t W2_p[t][n] * Wqk_p[d][aoff+t]   (f32 in, bf16 out).
__global__ __launch_bounds__(256) void weff_kernel(
    const float* __restrict__ Wiqk, const float* __restrict__ Wqi, const float* __restrict__ Wki,
    const float* __restrict__ Wdqk, const float* __restrict__ Wqd, const float* __restrict__ Wkd,
    u16t* __restrict__ weffT) {
  __shared__ float At[16][65];   // At[kk][nn]
  __shared__ float Bt[16][65];   // Bt[kk][dd]
  const int tid = threadIdx.x;
  const int n0 = blockIdx.x * 64;
  const int d0 = blockIdx.y * 64;
  const int p  = blockIdx.z;
  const float* A2  = (p == 0) ? Wqi : (p == 1) ? Wki : (p == 2) ? Wqd : Wkd;  // [t][n]
  const float* Wqk = (p < 2) ? Wiqk : Wdqk;                                    // [d][512]
  const int aoff = (p & 1) * 256;
  const int tx = tid & 15, ty = tid >> 4;

  float acc[4][4];
#pragma unroll
  for (int i = 0; i < 4; ++i)
#pragma unroll
    for (int j = 0; j < 4; ++j) acc[i][j] = 0.f;

  for (int k0 = 0; k0 < 256; k0 += 16) {
    __syncthreads();
    {
      int nn = tid & 63, kr = tid >> 6;
#pragma unroll
      for (int pass = 0; pass < 4; ++pass) {
        int kk = kr + pass * 4;
        At[kk][nn] = A2[(size_t)(k0 + kk) * 256 + n0 + nn];
      }
      int kk = tid & 15, dr = tid >> 4;
#pragma unroll
      for (int pass = 0; pass < 4; ++pass) {
        int dd = dr + pass * 16;
        Bt[kk][dd] = Wqk[(size_t)(d0 + dd) * 512 + aoff + k0 + kk];
      }
    }
    __syncthreads();
#pragma unroll
    for (int kk = 0; kk < 16; ++kk) {
      float a[4], b[4];
#pragma unroll
      for (int i = 0; i < 4; ++i) a[i] = At[kk][ty * 4 + i];
#pragma unroll
      for (int j = 0; j < 4; ++j) b[j] = Bt[kk][tx * 4 + j];
#pragma unroll
      for (int i = 0; i < 4; ++i)
#pragma unroll
        for (int j = 0; j < 4; ++j) acc[i][j] = fmaf(a[i], b[j], acc[i][j]);
    }
  }

#pragma unroll
  for (int i = 0; i < 4; ++i) {
    u16t h[4] = {f2bf(acc[i][0]), f2bf(acc[i][1]), f2bf(acc[i][2]), f2bf(acc[i][3])};
    *(uint2*)(&weffT[((size_t)(p * 256 + n0 + ty * 4 + i)) * 256 + d0 + tx * 4]) =
        *(const uint2*)h;
  }
}

// ---------------------------------------------------------------------------
// Projection GEMM: M=8192 (r=b*512+l), N=1024 (p,h,t), K=256, A/B both bf16
// rows (A from prep_kernel). Out -> qk[p][b][h][l][QKROW] + bias.
__global__ __launch_bounds__(256) void proj_kernel(
    const u16t* __restrict__ Abf, const u16t* __restrict__ weffT,
    const float* __restrict__ bq_inc, const float* __restrict__ bk_inc,
    const float* __restrict__ bq_dec, const float* __restrict__ bk_dec,
    u16t* __restrict__ qk) {
  __shared__ __align__(16) u16t As[128 * 40];
  __shared__ __align__(16) u16t Bs[128 * 40];
  const int t = threadIdx.x;
  const int n0 = blockIdx.x * 128;
  const int r0 = blockIdx.y * 128;
  const int bb = r0 >> 9;
  const int l0 = r0 & 511;
  const int lane = t & 63, wid = t >> 6;
  const int quad = lane >> 4, c15 = lane & 15;
  const int wm = wid >> 1, wn = wid & 1;

  f4v acc[4][4];
#pragma unroll
  for (int i = 0; i < 4; ++i)
#pragma unroll
    for (int j = 0; j < 4; ++j) acc[i][j] = f4v{0.f, 0.f, 0.f, 0.f};

  for (int k0 = 0; k0 < 256; k0 += 32) {
    __syncthreads();
#pragma unroll
    for (int i = 0; i < 2; ++i) {
      int c = t + i * 256;
      int m = c >> 2, off = (c & 3) * 8;
      *(uint4*)(&As[m * 40 + off]) =
          *(const uint4*)(Abf + (size_t)(r0 + m) * 256 + k0 + off);
      *(uint4*)(&Bs[m * 40 + off]) =
          *(const uint4*)(weffT + (size_t)(n0 + m) * 256 + k0 + off);
    }
    __syncthreads();
    s8v af[4], bf[4];
#pragma unroll
    for (int mi = 0; mi < 4; ++mi)
      af[mi] = *(const s8v*)(&As[(wm * 64 + mi * 16 + c15) * 40 + quad * 8]);
#pragma unroll
    for (int ni = 0; ni < 4; ++ni)
      bf[ni] = *(const s8v*)(&Bs[(wn * 64 + ni * 16 + c15) * 40 + quad * 8]);
#pragma unroll
    for (int mi = 0; mi < 4; ++mi)
#pragma unroll
      for (int ni = 0; ni < 4; ++ni)
        acc[mi][ni] = MFMA16(af[mi], bf[ni], acc[mi][ni], 0, 0, 0);
  }

  const float* biasP[4] = {bq_inc, bk_inc, bq_dec, bk_dec};
#pragma unroll
  for (int ni = 0; ni < 4; ++ni) {
    int n = n0 + wn * 64 + ni * 16 + c15;
    int p = n >> 8, h = (n >> 6) & 3, tt = n & 63, jj = n & 255;
    float bias = biasP[p][jj];
    u16t* dst = qk + (size_t)p * QKN72;
#pragma unroll
    for (int mi = 0; mi < 4; ++mi) {
#pragma unroll
      for (int reg = 0; reg < 4; ++reg) {
        int l = l0 + wm * 64 + mi * 16 + quad * 4 + reg;
        dst[((size_t)(bb * 4 + h) * 512 + l) * QKROW + tt] = f2bf(acc[mi][ni][reg] + bias);
      }
    }
  }
}

// ---------------------------------------------------------------------------
// Row softmax denominators. Block = 256 thr (4 waves), l-tile 128 (wave
// owns 32 l-rows across ALL m -> wave-local row sum, no cross-wave reduce).
// XCD-swizzled; padded LDS rows -> conflict-free fragment reads.
__global__ __launch_bounds__(256) void stats_kernel(
    const u16t* __restrict__ qk, const int* __restrict__ mask, float* __restrict__ invsum) {
  __shared__ __align__(16) u16t Qs[128 * QKROW];
  __shared__ __align__(16) u16t Ks[128 * QKROW];
  __shared__ int mrow[512];
  const int t = threadIdx.x;
  const int id = blockIdx.x;               // 512 blocks
  const int xcd = id & 7, r1 = id >> 3;    // r1: [0,64)
  const int bb = xcd * 2 + (r1 & 1);
  const int rem = r1 >> 1;                 // [0,32)
  const int pp = rem >> 4, h = (rem >> 2) & 3, lt = rem & 3;
  const int l0 = lt * 128;

  const u16t* Q = qk + (size_t)(2 * pp) * QKN72 + ((size_t)(bb * 4 + h) * 512 + l0) * QKROW;
  const u16t* K = qk + (size_t)(2 * pp + 1) * QKN72 + ((size_t)(bb * 4 + h) * 512) * QKROW;

  // stage Q tile (128 x 144 B = 1152 uint4) + mask row
  for (int i = t; i < 1152; i += 256)
    *(uint4*)(&Qs[i * 8]) = *(const uint4*)(Q + i * 8);
  mrow[t] = mask[bb * 512 + t];
  mrow[t + 256] = mask[bb * 512 + t + 256];

  const int lane = t & 63, wid = t >> 6;
  const int quad = lane >> 4, c15 = lane & 15;

  float rs[2][4] = {{0.f, 0.f, 0.f, 0.f}, {0.f, 0.f, 0.f, 0.f}};
  for (int m0 = 0; m0 < 512; m0 += 128) {
    __syncthreads();   // Ks free (and Q/mrow visible on first iter)
    for (int i = t; i < 1152; i += 256)
      *(uint4*)(&Ks[i * 8]) = *(const uint4*)(K + (size_t)m0 * QKROW + i * 8);
    __syncthreads();
    s8v a[2][2];
#pragma unroll
    for (int j = 0; j < 2; ++j) {
      int row = wid * 32 + j * 16 + c15;
      a[j][0] = *(const s8v*)(&Qs[row * QKROW + quad * 8]);
      a[j][1] = *(const s8v*)(&Qs[row * QKROW + 32 + quad * 8]);
    }
#pragma unroll
    for (int nt = 0; nt < 8; ++nt) {
      int mloc = nt * 16 + c15;
      s8v b0 = *(const s8v*)(&Ks[mloc * QKROW + quad * 8]);
      s8v b1 = *(const s8v*)(&Ks[mloc * QKROW + 32 + quad * 8]);
      float vm = mrow[m0 + mloc] ? 0.f : 1.f;
#pragma unroll
      for (int j = 0; j < 2; ++j) {
        f4v sacc = f4v{0.f, 0.f, 0.f, 0.f};
        sacc = MFMA16(a[j][0], b0, sacc, 0, 0, 0);
        sacc = MFMA16(a[j][1], b1, sacc, 0, 0, 0);
#pragma unroll
        for (int reg = 0; reg < 4; ++reg)
          rs[j][reg] += vm * __expf(sacc[reg] * 0.125f);
      }
    }
  }
#pragma unroll
  for (int j = 0; j < 2; ++j)
#pragma unroll
    for (int reg = 0; reg < 4; ++reg) {
#pragma unroll
      for (int off = 1; off < 16; off <<= 1) rs[j][reg] += __shfl_xor(rs[j][reg], off);
    }
  if (c15 == 0) {
#pragma unroll
    for (int j = 0; j < 2; ++j)
#pragma unroll
      for (int reg = 0; reg < 4; ++reg) {
        int l = l0 + wid * 32 + j * 16 + quad * 4 + reg;
        invsum[((size_t)(pp * 16 + bb) * 4 + h) * 512 + l] = 1.0f / rs[j][reg];
      }
  }
}

// ---------------------------------------------------------------------------
// Final fused kernel, R3 geometry (l16 x m128, 4 waves, grid 2048) +
// XCD swizzle + padded conflict-free LDS.
__global__ __launch_bounds__(256) void final_kernel(
    const u16t* __restrict__ qk, const int* __restrict__ mask, const float* __restrict__ invsum,
    const int* __restrict__ src_bond, const float* __restrict__ Wc, const float* __restrict__ bc,
    float* __restrict__ out) {
  __shared__ __align__(16) u16t Ks[128 * QKROW];
  __shared__ int bondsL[96];   // 16 l x 6
  __shared__ int padls[16];
  const int t = threadIdx.x;
  const int id = blockIdx.x;               // 2048 blocks
  const int xcd = id & 7, r1 = id >> 3;    // r1: [0,256)
  const int bb = xcd * 2 + (r1 & 1);
  const int tile = r1 >> 1;                // [0,128)
  const int mt = tile & 3, lt = tile >> 2;
  const int m0 = mt * 128;
  const int l0 = lt * 16;

  if (t < 96) bondsL[t] = src_bond[(size_t)(bb * 512 + l0 + t / 6) * 6 + (t % 6)];
  else if (t < 112) padls[t - 96] = mask[bb * 512 + l0 + (t - 96)];

  const int lane = t & 63, wid = t >> 6;
  const int quad = lane >> 4, c15 = lane & 15;

  int mval[2];
  mval[0] = mask[bb * 512 + m0 + wid * 32 + c15];
  mval[1] = mask[bb * 512 + m0 + wid * 32 + 16 + c15];

  float Wf[16];
#pragma unroll
  for (int i = 0; i < 16; ++i) Wf[i] = Wc[i];

  float dacc[2][4][4];   // [msub][reg][cls]
#pragma unroll
  for (int a = 0; a < 2; ++a)
#pragma unroll
    for (int r = 0; r < 4; ++r)
#pragma unroll
      for (int c = 0; c < 4; ++c) dacc[a][r][c] = 0.f;

  for (int q = 0; q < 8; ++q) {
    const int pp = q >> 2, h = q & 3;
    __syncthreads();   // Ks free (first iter: bonds/padls visible)
    const u16t* Kb = qk + (size_t)(2 * pp + 1) * QKN72 + ((size_t)(bb * 4 + h) * 512 + m0) * QKROW;
    for (int i = t; i < 1152; i += 256)
      *(uint4*)(&Ks[i * 8]) = *(const uint4*)(Kb + i * 8);
    const u16t* Qb = qk + (size_t)(2 * pp) * QKN72 + ((size_t)(bb * 4 + h) * 512 + l0) * QKROW;
    s8v a0 = *(const s8v*)(Qb + c15 * QKROW + quad * 8);
    s8v a1 = *(const s8v*)(Qb + c15 * QKROW + 32 + quad * 8);
    float iv[4];
    const float* ivb = invsum + ((size_t)(pp * 16 + bb) * 4 + h) * 512 + l0 + quad * 4;
#pragma unroll
    for (int reg = 0; reg < 4; ++reg) iv[reg] = ivb[reg];
    __syncthreads();
    const float sgn = pp ? -1.f : 1.f;
#pragma unroll
    for (int ms = 0; ms < 2; ++ms) {
      int mloc = wid * 32 + ms * 16 + c15;
      s8v b0 = *(const s8v*)(&Ks[mloc * QKROW + quad * 8]);
      s8v b1 = *(const s8v*)(&Ks[mloc * QKROW + 32 + quad * 8]);
      f4v sacc = f4v{0.f, 0.f, 0.f, 0.f};
      sacc = MFMA16(a0, b0, sacc, 0, 0, 0);
      sacc = MFMA16(a1, b1, sacc, 0, 0, 0);
      const float vm = mval[ms] ? 0.f : sgn;
#pragma unroll
      for (int reg = 0; reg < 4; ++reg) {
        float P = __expf(sacc[reg] * 0.125f) * iv[reg] * vm;
#pragma unroll
        for (int c = 0; c < 4; ++c)
          dacc[ms][reg][c] = fmaf(P, Wf[h * 4 + c], dacc[ms][reg][c]);
      }
    }
  }

  float bcF[4];
#pragma unroll
  for (int c = 0; c < 4; ++c) bcF[c] = bc[c];
  const float lgH = logf(0.7f + 1e-6f);   // one-hot hit
  const float lgM = logf(0.1f + 1e-6f);   // one-hot miss
  const float lgU = logf(0.25f + 1e-6f);  // count >= MAX_DIFF -> uniform

#pragma unroll
  for (int ms = 0; ms < 2; ++ms) {
    int m = m0 + wid * 32 + ms * 16 + c15;
    bool padm = (mval[ms] == 0);
#pragma unroll
    for (int reg = 0; reg < 4; ++reg) {
      int lloc = quad * 4 + reg;
      int l = l0 + lloc;
      bool pm = padm && (padls[lloc] == 0);
      int cnt = 0;
#pragma unroll
      for (int j = 0; j < 6; ++j) cnt += (bondsL[lloc * 6 + j] == m) ? 1 : 0;
      int cls = (pm && (m != l)) ? cnt : 0;
      float v[4];
#pragma unroll
      for (int c = 0; c < 4; ++c) {
        float lp = (cls >= 4) ? lgU : ((c == cls) ? lgH : lgM);
        float dv = pm ? 4.f * (dacc[ms][reg][c] + bcF[c]) : 0.f;
        v[c] = lp + dv;
      }
      float4 o = make_float4(v[0], v[1], v[2], v[3]);
      *(float4*)(&out[((size_t)(bb * 512 + l) * 512 + m) * 4]) = o;
    }
  }
}

// ---------------------------------------------------------------------------
extern "C" void kernel_launch(void* const* d_in, const int* in_sizes, int n_in,
                              void* d_out, int out_size, void* d_ws, size_t ws_size,
                              hipStream_t stream) {
  (void)in_sizes; (void)n_in; (void)out_size; (void)ws_size;
  const float* emb      = (const float*)d_in[0];
  const int*   src_bond = (const int*)d_in[1];
  const int*   mask_raw = (const int*)d_in[2];
  const float* W_inc_qk = (const float*)d_in[3];
  const float* Wq_inc   = (const float*)d_in[4];
  const float* bq_inc   = (const float*)d_in[5];
  const float* Wk_inc   = (const float*)d_in[6];
  const float* bk_inc   = (const float*)d_in[7];
  const float* W_dec_qk = (const float*)d_in[8];
  const float* Wq_dec   = (const float*)d_in[9];
  const float* bq_dec   = (const float*)d_in[10];
  const float* Wk_dec   = (const float*)d_in[11];
  const float* bk_dec   = (const float*)d_in[12];
  const float* Wc       = (const float*)d_in[13];
  const float* bc       = (const float*)d_in[14];
  float* out = (float*)d_out;

  char* ws = (char*)d_ws;
  int*   wsMask = (int*)ws;                                  // 32 KiB
  u16t*  weffT  = (u16t*)(ws + 32768);                       // 512 KiB
  u16t*  Abf    = (u16t*)(ws + 557056);                      // 4 MiB
  u16t*  qk     = (u16t*)(ws + 557056 + 4194304);            // 4 x 4.5 MiB (padded)
  float* invsum = (float*)(ws + 557056 + 4194304 + (size_t)4 * QKN72 * 2);

  hipLaunchKernelGGL(mask_norm,   dim3(32),      dim3(256), 0, stream, mask_raw, wsMask);
  hipLaunchKernelGGL(prep_kernel, dim3(1024),    dim3(256), 0, stream, emb, Abf);
  hipLaunchKernelGGL(weff_kernel, dim3(4, 4, 4), dim3(256), 0, stream,
                     W_inc_qk, Wq_inc, Wk_inc, W_dec_qk, Wq_dec, Wk_dec, weffT);
  hipLaunchKernelGGL(proj_kernel, dim3(8, 64),   dim3(256), 0, stream,
                     Abf, weffT, bq_inc, bk_inc, bq_dec, bk_dec, qk);
  hipLaunchKernelGGL(stats_kernel, dim3(512),    dim3(256), 0, stream, qk, wsMask, invsum);
  hipLaunchKernelGGL(final_kernel, dim3(2048),   dim3(256), 0, stream,
                     qk, wsMask, invsum, src_bond, Wc, bc, out);
}